// Round 1
// baseline (563.973 us; speedup 1.0000x reference)
//
#include <hip/hip_runtime.h>
#include <math.h>

// Problem constants (match reference)
#define BN 32768
#define DN 512
#define SN 32
#define LN 8
#define KN 256
#define N2 65536   // 2*BN

// workspace layout (byte offsets)
#define OFF_SUMS    0           // float[KN*DN]  512KB
#define OFF_CENTT   (524288)    // float[DN*KN]  512KB  ([d][g])
#define OFF_COUNTS  (1048576)   // int[KN]
#define OFF_SUMQ    (1049600)   // float[KN]
#define OFF_INVD    (1050624)   // float[KN]
#define OFF_LOSS    (1051648)   // float[1]
#define WS_ZERO_BYTES (1051652)

__device__ __forceinline__ float atomAddF(float* p, float v) {
  return unsafeAtomicAdd(p, v);   // hw global_atomic_add_f32 on gfx950
}

// ---- k1: counts + per-group feature sums (reads X once, 128MB) ----
__global__ __launch_bounds__(256) void k1_sums(const float* __restrict__ X,
    const int* __restrict__ subject, const int* __restrict__ labels,
    float* __restrict__ sums, int* __restrict__ counts) {
  const int b0 = blockIdx.x * 16;
  const int t = threadIdx.x;
  for (int r = 0; r < 16; ++r) {
    const int b = b0 + r;
    const int g = subject[b] * LN + labels[b];
    const float* x = X + (size_t)b * (2 * DN);
    // both views summed together: feat rows b and b+BN share gid
    float v0 = x[t] + x[t + DN];
    float v1 = x[t + 256] + x[t + 256 + DN];
    atomAddF(&sums[g * DN + t], v0);
    atomAddF(&sums[g * DN + t + 256], v1);
    if (t == 0) atomicAdd(&counts[g], 2);
  }
}

// ---- k2: transposed centroid centT[d][g] = sums[g][d]/counts[g] ----
__global__ __launch_bounds__(256) void k2_centT(const float* __restrict__ sums,
    const int* __restrict__ counts, float* __restrict__ centT) {
  const int i = blockIdx.x * 256 + threadIdx.x;   // over DN*KN
  const int g = i & (KN - 1);
  const int d = i >> 8;
  centT[i] = sums[g * DN + d] / (float)counts[g];
}

// ---- k3: per-row distance to own centroid; accumulate sum of dist^0.25 ----
__global__ __launch_bounds__(256) void k3_dist(const float* __restrict__ X,
    const int* __restrict__ subject, const int* __restrict__ labels,
    const float* __restrict__ sums, const int* __restrict__ counts,
    float* __restrict__ sumq) {
  const int row = blockIdx.x * 4 + (threadIdx.x >> 6);
  const int lane = threadIdx.x & 63;
  const int b = row & (BN - 1);
  const int v = row >> 15;   // row / BN
  const float* f = X + (size_t)b * (2 * DN) + v * DN;
  const int g = subject[b] * LN + labels[b];
  const float invc = 1.0f / (float)counts[g];
  const float* s = sums + g * DN;
  float ss = 0.f;
#pragma unroll
  for (int k = 0; k < 8; ++k) {
    int d = lane + k * 64;
    float diff = f[d] - s[d] * invc;
    ss += diff * diff;
  }
#pragma unroll
  for (int off = 32; off > 0; off >>= 1) ss += __shfl_down(ss, off, 64);
  // dist = sqrt(ss); sqrt(dist) = ss^0.25
  if (lane == 0) atomAddF(&sumq[g], sqrtf(sqrtf(ss)));
}

// ---- k4: density (dens, dmax-fill, quantile clip, normalize) ----
__global__ __launch_bounds__(256) void k4_density(const float* __restrict__ sumq,
    const int* __restrict__ counts, float* __restrict__ invd) {
  __shared__ float sv[256];
  __shared__ float st[256];
  const int t = threadIdx.x;
  const int cnt = counts[t];
  const bool valid = cnt > 1;
  float dens = 0.f;
  if (valid) dens = (sumq[t] / (float)cnt) / logf((float)cnt + 10.f);
  sv[t] = valid ? dens : -INFINITY;
  __syncthreads();
  for (int s = 128; s > 0; s >>= 1) {
    if (t < s) sv[t] = fmaxf(sv[t], sv[t + s]);
    __syncthreads();
  }
  const float dmax = sv[0];
  __syncthreads();
  const float d0 = valid ? dens : dmax;
  sv[t] = d0;
  __syncthreads();
  // rank-sort 256 values (stable, unique ranks)
  int rank = 0;
  for (int j = 0; j < 256; ++j) {
    float vj = sv[j];
    rank += (vj < d0) || (vj == d0 && j < t);
  }
  st[rank] = d0;
  __syncthreads();
  // q at 0.1*(256-1)=25.5 and 0.9*255=229.5 -> midpoint interpolation
  const float q10 = 0.5f * (st[25] + st[26]);
  const float q90 = 0.5f * (st[229] + st[230]);
  const float dc = fminf(fmaxf(d0, q10), q90);
  sv[t] = dc;
  __syncthreads();
  for (int s = 128; s > 0; s >>= 1) {
    if (t < s) sv[t] += sv[t + s];
    __syncthreads();
  }
  const float mean = sv[0] * (1.0f / 256.f);
  // density = 0.1*dc/mean; store reciprocal
  invd[t] = mean / (0.1f * dc);
}

// ---- k5: sim = feat@centT * invd, row-max, masked softmax loss ----
// block: 256 threads = 8 row-threads x 32 group-threads; 64 rows x 256 groups
// per-thread 8x8 f32 accumulators.
#define FPAD 36
__global__ __launch_bounds__(256) void k5_loss(const float* __restrict__ X,
    const int* __restrict__ subject, const int* __restrict__ labels,
    const float* __restrict__ centT, const float* __restrict__ invd,
    float* __restrict__ losssum) {
  __shared__ float ldsF[64 * FPAD];   // [row][c] padded
  __shared__ float ldsC[32 * 256];    // [c][g]
  const int t = threadIdx.x;
  const int gq = t & 31;              // owns groups gq*8 .. gq*8+7
  const int rq = t >> 5;              // owns rows rq*8 .. rq*8+7 (block-local)
  const int rowbase = blockIdx.x * 64;
  const int v = rowbase >> 15;
  const int bbase = rowbase & (BN - 1);
  const float* Xb = X + (size_t)bbase * (2 * DN) + v * DN;

  float acc[8][8];
#pragma unroll
  for (int i = 0; i < 8; ++i)
#pragma unroll
    for (int j = 0; j < 8; ++j) acc[i][j] = 0.f;

  for (int d0 = 0; d0 < DN; d0 += 32) {
    __syncthreads();
    // stage feat tile: 64 rows x 32 cols, float4 loads, padded LDS rows
#pragma unroll
    for (int k = 0; k < 2; ++k) {
      int j4 = k * 256 + t;          // over 512 float4
      int r = j4 >> 3;
      int c4 = j4 & 7;
      float4 val = *(const float4*)(Xb + (size_t)r * (2 * DN) + d0 + c4 * 4);
      *(float4*)(&ldsF[r * FPAD + c4 * 4]) = val;   // FPAD*4B = 144B, 16B aligned
    }
    // stage centroid tile: 32 x 256 contiguous
#pragma unroll
    for (int k = 0; k < 8; ++k) {
      ((float4*)ldsC)[k * 256 + t] = ((const float4*)(centT + (size_t)d0 * 256))[k * 256 + t];
    }
    __syncthreads();
#pragma unroll
    for (int c = 0; c < 32; ++c) {
      float a[8], bb[8];
#pragma unroll
      for (int j = 0; j < 8; ++j) bb[j] = ldsC[c * 256 + gq * 8 + j];
#pragma unroll
      for (int i = 0; i < 8; ++i) a[i] = ldsF[(rq * 8 + i) * FPAD + c];
#pragma unroll
      for (int i = 0; i < 8; ++i)
#pragma unroll
        for (int j = 0; j < 8; ++j)
          acc[i][j] = fmaf(a[i], bb[j], acc[i][j]);
    }
  }

  float iv[8];
#pragma unroll
  for (int j = 0; j < 8; ++j) iv[j] = invd[gq * 8 + j];

  float lsum = 0.f;
#pragma unroll
  for (int i = 0; i < 8; ++i) {
    const int R = rowbase + rq * 8 + i;
    const int b = R & (BN - 1);
    const int lab = labels[b];
    const int sub = subject[b];
    float s[8];
    float m = -INFINITY;
#pragma unroll
    for (int j = 0; j < 8; ++j) {
      s[j] = acc[i][j] * iv[j];
      m = fmaxf(m, s[j]);
    }
    // row-max across the 32 group-threads (lanes 0-31 / 32-63 are distinct rq)
#pragma unroll
    for (int off = 1; off < 32; off <<= 1) m = fmaxf(m, __shfl_xor(m, off, 64));
    // this thread's only candidate positive has local index j == lab (g = gq*8+j, g%8==lab)
    float sl = s[0];
#pragma unroll
    for (int j = 1; j < 8; ++j) sl = (lab == j) ? s[j] : sl;
    const bool pos = (gq != sub);
    float e = pos ? expf(sl - m) : 0.f;
    float z = pos ? (sl - m) : 0.f;
#pragma unroll
    for (int off = 1; off < 32; off <<= 1) {
      e += __shfl_xor(e, off, 64);
      z += __shfl_xor(z, off, 64);
    }
    // 225 non-positive entries pinned at 0 contribute exp(0)=1 each; 31 positives
    float loss = logf(225.f + e) - z * (1.0f / 31.0f);
    if (gq == 0) lsum += loss;
  }
  if (gq == 0) atomAddF(losssum, lsum);
}

// ---- k6: final mean ----
__global__ void k6_final(const float* __restrict__ losssum, float* __restrict__ out) {
  out[0] = losssum[0] * (1.0f / (float)N2);
}

extern "C" void kernel_launch(void* const* d_in, const int* in_sizes, int n_in,
                              void* d_out, int out_size, void* d_ws, size_t ws_size,
                              hipStream_t stream) {
  const float* X = (const float*)d_in[0];
  const int* subject = (const int*)d_in[1];
  const int* labels = (const int*)d_in[2];
  char* ws = (char*)d_ws;
  float* sums = (float*)(ws + OFF_SUMS);
  float* centT = (float*)(ws + OFF_CENTT);
  int* counts = (int*)(ws + OFF_COUNTS);
  float* sumq = (float*)(ws + OFF_SUMQ);
  float* invd = (float*)(ws + OFF_INVD);
  float* losssum = (float*)(ws + OFF_LOSS);

  hipMemsetAsync(d_ws, 0, WS_ZERO_BYTES, stream);
  k1_sums<<<BN / 16, 256, 0, stream>>>(X, subject, labels, sums, counts);
  k2_centT<<<(DN * KN) / 256, 256, 0, stream>>>(sums, counts, centT);
  k3_dist<<<N2 / 4, 256, 0, stream>>>(X, subject, labels, sums, counts, sumq);
  k4_density<<<1, 256, 0, stream>>>(sumq, counts, invd);
  k5_loss<<<N2 / 64, 256, 0, stream>>>(X, subject, labels, centT, invd, losssum);
  k6_final<<<1, 1, 0, stream>>>(losssum, (float*)d_out);
}

// Round 2
// 481.414 us; speedup vs baseline: 1.1715x; 1.1715x over previous
//
#include <hip/hip_runtime.h>
#include <math.h>

// Problem constants
#define BN 32768
#define DN 512
#define SN 32
#define LN 8
#define KN 256
#define N2 65536   // 2*BN
#define CHUNKS 32
#define RPC 1024   // rows per chunk (BN / CHUNKS)

typedef __attribute__((ext_vector_type(8))) short bf16x8;
typedef __attribute__((ext_vector_type(4))) float f32x4;

// workspace layout (byte offsets)
#define OFF_XBF     0ull                      // ushort[N2*DN]      67108864
#define OFF_PART    67108864ull               // float[CHUNKS*KN*DN] 16777216
#define OFF_SUMS    83886080ull               // float[KN*DN]        524288
#define OFF_CENTB   84410368ull               // ushort[KN*DN]       262144
#define OFF_GID     84672512ull               // int[BN]             131072
#define OFF_COUNTS  84803584ull               // int[KN]
#define OFF_SUMQ    84804608ull               // float[KN]
#define OFF_INVD    84805632ull               // float[KN]
#define OFF_LOSS    84806656ull               // float[1]
#define ZERO_OFF    OFF_COUNTS
#define ZERO_BYTES  (84806660ull - OFF_COUNTS)

__device__ __forceinline__ float atomAddF(float* p, float v) {
  return unsafeAtomicAdd(p, v);   // hw global_atomic_add_f32
}

__device__ __forceinline__ ushort f2bf(float x) {
  union { float f; unsigned u; } v; v.f = x;
  unsigned u = v.u;
  unsigned r = (u + 0x7fffu + ((u >> 16) & 1u)) >> 16;  // RNE
  return (ushort)r;
}

__device__ __forceinline__ float bf2f(ushort x) {
  union { unsigned u; float f; } v; v.u = ((unsigned)x) << 16;
  return v.f;
}

// ---- k0: gid + counts histogram ----
__global__ __launch_bounds__(256) void k0_gid(const int* __restrict__ subject,
    const int* __restrict__ labels, int* __restrict__ gid, int* __restrict__ counts) {
  __shared__ int hist[KN];
  hist[threadIdx.x] = 0;
  __syncthreads();
  const int b0 = blockIdx.x * 1024;
  for (int i = threadIdx.x; i < 1024; i += 256) {
    int b = b0 + i;
    int g = subject[b] * LN + labels[b];
    gid[b] = g;
    atomicAdd(&hist[g], 1);
  }
  __syncthreads();
  if (hist[threadIdx.x]) atomicAdd(&counts[threadIdx.x], 2 * hist[threadIdx.x]);
}

// ---- k1: convert X -> bf16 feat layout, accumulate per-(chunk,slice) group sums ----
// grid: 256 blocks = 32 row-chunks x 8 dim-slices (64 dims each)
__global__ __launch_bounds__(256) void k1_partial(const float* __restrict__ X,
    const int* __restrict__ gid, ushort* __restrict__ Xb, float* __restrict__ partial) {
  __shared__ float accs[KN * 64];   // 64 KB
  const int slice = blockIdx.x & 7;
  const int chunk = blockIdx.x >> 3;
  const int t = threadIdx.x;
  const int d = t & 63;
  const int rv = t >> 6;            // 0..3: 4 rows in flight
  for (int j = t; j < KN * 64; j += 256) accs[j] = 0.f;
  __syncthreads();
  const int b0 = chunk * RPC;
  for (int r0 = 0; r0 < RPC; r0 += 4) {
    const int b = b0 + r0 + rv;
    const int g = gid[b];
    const float* xp = X + (size_t)b * 1024 + slice * 64 + d;
    float x0 = xp[0];
    float x1 = xp[DN];
    Xb[(size_t)b * DN + slice * 64 + d] = f2bf(x0);
    Xb[(size_t)(b + BN) * DN + slice * 64 + d] = f2bf(x1);
    atomicAdd(&accs[g * 64 + d], x0 + x1);
  }
  __syncthreads();
  for (int j = t; j < KN * 64; j += 256) {
    int g = j >> 6, dd = j & 63;
    partial[(size_t)chunk * (KN * DN) + g * DN + slice * 64 + dd] = accs[j];
  }
}

// ---- k1b: reduce partials -> sums[g][d] ----
__global__ __launch_bounds__(256) void k1b_reduce(const float* __restrict__ partial,
    float* __restrict__ sums) {
  const int i = blockIdx.x * 256 + threadIdx.x;   // over KN*DN
  float s = 0.f;
#pragma unroll
  for (int c = 0; c < CHUNKS; ++c) s += partial[(size_t)c * (KN * DN) + i];
  sums[i] = s;
}

// ---- k2: bf16 centroids cent[g][d] ----
__global__ __launch_bounds__(256) void k2_cent(const float* __restrict__ sums,
    const int* __restrict__ counts, ushort* __restrict__ centB) {
  const int i = blockIdx.x * 256 + threadIdx.x;   // [g][d]
  const int g = i >> 9;
  centB[i] = f2bf(sums[i] / (float)counts[g]);
}

// ---- k3: per-row distance^0.25 accumulation (reads bf16 X copy) ----
__global__ __launch_bounds__(256) void k3_dist(const ushort* __restrict__ Xb,
    const int* __restrict__ gid, const float* __restrict__ sums,
    const int* __restrict__ counts, float* __restrict__ sumq) {
  const int row = blockIdx.x * 4 + (threadIdx.x >> 6);
  const int lane = threadIdx.x & 63;
  const int b = row & (BN - 1);
  const int g = gid[b];
  const float invc = 1.0f / (float)counts[g];
  int4 chunk = *(const int4*)(Xb + (size_t)row * DN + lane * 8);
  const ushort* us = (const ushort*)&chunk;
  const float* s = sums + g * DN + lane * 8;
  float4 s0 = *(const float4*)s;
  float4 s1 = *(const float4*)(s + 4);
  float cs[8] = {s0.x, s0.y, s0.z, s0.w, s1.x, s1.y, s1.z, s1.w};
  float ss = 0.f;
#pragma unroll
  for (int k = 0; k < 8; ++k) {
    float diff = bf2f(us[k]) - cs[k] * invc;
    ss += diff * diff;
  }
#pragma unroll
  for (int off = 32; off > 0; off >>= 1) ss += __shfl_down(ss, off, 64);
  if (lane == 0) atomAddF(&sumq[g], sqrtf(sqrtf(ss)));
}

// ---- k4: density -> invd ----
__global__ __launch_bounds__(256) void k4_density(const float* __restrict__ sumq,
    const int* __restrict__ counts, float* __restrict__ invd) {
  __shared__ float sv[256];
  __shared__ float st[256];
  const int t = threadIdx.x;
  const int cnt = counts[t];
  const bool valid = cnt > 1;
  float dens = 0.f;
  if (valid) dens = (sumq[t] / (float)cnt) / logf((float)cnt + 10.f);
  sv[t] = valid ? dens : -INFINITY;
  __syncthreads();
  for (int s = 128; s > 0; s >>= 1) {
    if (t < s) sv[t] = fmaxf(sv[t], sv[t + s]);
    __syncthreads();
  }
  const float dmax = sv[0];
  __syncthreads();
  const float d0 = valid ? dens : dmax;
  sv[t] = d0;
  __syncthreads();
  int rank = 0;
  for (int j = 0; j < 256; ++j) {
    float vj = sv[j];
    rank += (vj < d0) || (vj == d0 && j < t);
  }
  st[rank] = d0;
  __syncthreads();
  const float q10 = 0.5f * (st[25] + st[26]);
  const float q90 = 0.5f * (st[229] + st[230]);
  const float dc = fminf(fmaxf(d0, q10), q90);
  sv[t] = dc;
  __syncthreads();
  for (int s = 128; s > 0; s >>= 1) {
    if (t < s) sv[t] += sv[t + s];
    __syncthreads();
  }
  const float mean = sv[0] * (1.0f / 256.f);
  invd[t] = mean / (0.1f * dc);
}

// ---- k5: MFMA GEMM (128 rows x 256 groups, K=512) + fused softmax loss ----
// 4 waves; wave w owns groups [w*64, w*64+64): 8 M-tiles x 4 N-tiles of 16x16x32.
// LDS rows padded to 144B -> conflict-free ds_read_b128.
#define ARS 144   // A row stride bytes (64 bf16 + 8 pad)
#define BRS 144
__global__ __launch_bounds__(256, 2) void k5_mfma(const ushort* __restrict__ Xb,
    const ushort* __restrict__ centB, const int* __restrict__ subject,
    const int* __restrict__ labels, const float* __restrict__ invd,
    float* __restrict__ losssum) {
  __shared__ char smem[128 * ARS + 256 * BRS + 1024];  // 18432 + 36864 + labels/subs
  char* ldsA = smem;                 // [128][144B]
  char* ldsB = smem + 128 * ARS;     // [256][144B]
  float* maxbuf = (float*)smem;      // epilogue aliases ldsA: [4][128]
  float* gmax = (float*)(smem + 2048);    // [128]
  float* ebuf = (float*)(smem + 2560);    // [4][128]
  float* zbuf = (float*)(smem + 4608);    // [4][128]
  int* labs = (int*)(smem + 128 * ARS + 256 * BRS);
  int* subs = labs + 128;

  const int t = threadIdx.x;
  const int w = t >> 6;
  const int lane = t & 63;
  const int quad = lane >> 4;
  const int n16 = lane & 15;
  const int rowbase = blockIdx.x * 128;

  if (t < 128) {
    int b = (rowbase + t) & (BN - 1);
    labs[t] = labels[b];
    subs[t] = subject[b];
  }

  f32x4 acc[8][4];
#pragma unroll
  for (int mt = 0; mt < 8; ++mt)
#pragma unroll
    for (int nt = 0; nt < 4; ++nt) acc[mt][nt] = (f32x4){0.f, 0.f, 0.f, 0.f};

  const ushort* Arow = Xb + (size_t)rowbase * DN;

  for (int k0 = 0; k0 < DN; k0 += 64) {
    __syncthreads();
    // stage A: 128 rows x 64 k (1024 16B chunks)
#pragma unroll
    for (int i = 0; i < 4; ++i) {
      int j = t + i * 256;
      int r = j >> 3, c = j & 7;
      *(int4*)(ldsA + r * ARS + c * 16) =
          *(const int4*)(Arow + (size_t)r * DN + k0 + c * 8);
    }
    // stage B: 256 groups x 64 k (2048 chunks)
#pragma unroll
    for (int i = 0; i < 8; ++i) {
      int j = t + i * 256;
      int g = j >> 3, c = j & 7;
      *(int4*)(ldsB + g * BRS + c * 16) =
          *(const int4*)(centB + (size_t)g * DN + k0 + c * 8);
    }
    __syncthreads();
#pragma unroll
    for (int s = 0; s < 2; ++s) {
      bf16x8 bfr[4];
#pragma unroll
      for (int nt = 0; nt < 4; ++nt) {
        int g = w * 64 + nt * 16 + n16;
        bfr[nt] = *(bf16x8*)(ldsB + g * BRS + s * 64 + quad * 16);
      }
#pragma unroll
      for (int mt = 0; mt < 8; ++mt) {
        bf16x8 afr = *(bf16x8*)(ldsA + (mt * 16 + n16) * ARS + s * 64 + quad * 16);
#pragma unroll
        for (int nt = 0; nt < 4; ++nt)
          acc[mt][nt] = __builtin_amdgcn_mfma_f32_16x16x32_bf16(afr, bfr[nt], acc[mt][nt], 0, 0, 0);
      }
    }
  }

  float iv[4];
#pragma unroll
  for (int nt = 0; nt < 4; ++nt) iv[nt] = invd[w * 64 + nt * 16 + n16];

  __syncthreads();   // GEMM LDS reads done; safe to alias ldsA for epilogue

  // pass 1: per-row max over this wave's 64 groups, then global over waves
#pragma unroll
  for (int mt = 0; mt < 8; ++mt) {
#pragma unroll
    for (int r = 0; r < 4; ++r) {
      float mm = -INFINITY;
#pragma unroll
      for (int nt = 0; nt < 4; ++nt) mm = fmaxf(mm, acc[mt][nt][r] * iv[nt]);
#pragma unroll
      for (int off = 1; off < 16; off <<= 1) mm = fmaxf(mm, __shfl_xor(mm, off, 64));
      if (n16 == 0) maxbuf[w * 128 + mt * 16 + quad * 4 + r] = mm;
    }
  }
  __syncthreads();
  if (t < 128)
    gmax[t] = fmaxf(fmaxf(maxbuf[t], maxbuf[128 + t]),
                    fmaxf(maxbuf[256 + t], maxbuf[384 + t]));
  __syncthreads();

  // pass 2: positive-sim exp/linear sums per row
#pragma unroll
  for (int mt = 0; mt < 8; ++mt) {
#pragma unroll
    for (int r = 0; r < 4; ++r) {
      const int row = mt * 16 + quad * 4 + r;
      const float gm = gmax[row];
      const int lab = labs[row];
      const int sub = subs[row];
      float e = 0.f, z = 0.f;
      if ((n16 & 7) == lab) {
#pragma unroll
        for (int nt = 0; nt < 4; ++nt) {
          int gdiv8 = w * 8 + nt * 2 + (n16 >> 3);
          if (gdiv8 != sub) {
            float sv = acc[mt][nt][r] * iv[nt] - gm;
            e += expf(sv);
            z += sv;
          }
        }
      }
#pragma unroll
      for (int off = 1; off < 16; off <<= 1) {
        e += __shfl_xor(e, off, 64);
        z += __shfl_xor(z, off, 64);
      }
      if (n16 == 0) {
        ebuf[w * 128 + row] = e;
        zbuf[w * 128 + row] = z;
      }
    }
  }
  __syncthreads();

  float lsum = 0.f;
  if (t < 128) {
    float e = ebuf[t] + ebuf[128 + t] + ebuf[256 + t] + ebuf[384 + t];
    float z = zbuf[t] + zbuf[128 + t] + zbuf[256 + t] + zbuf[384 + t];
    // 225 masked-out entries pinned at 0 -> exp(0)=1 each; 31 positives
    lsum = logf(225.f + e) - z * (1.0f / 31.0f);
  }
#pragma unroll
  for (int off = 32; off > 0; off >>= 1) lsum += __shfl_down(lsum, off, 64);
  if (lane == 0 && lsum != 0.f) atomAddF(losssum, lsum);
}

// ---- k6: final mean ----
__global__ void k6_final(const float* __restrict__ losssum, float* __restrict__ out) {
  out[0] = losssum[0] * (1.0f / (float)N2);
}

extern "C" void kernel_launch(void* const* d_in, const int* in_sizes, int n_in,
                              void* d_out, int out_size, void* d_ws, size_t ws_size,
                              hipStream_t stream) {
  const float* X = (const float*)d_in[0];
  const int* subject = (const int*)d_in[1];
  const int* labels = (const int*)d_in[2];
  char* ws = (char*)d_ws;
  ushort* Xb = (ushort*)(ws + OFF_XBF);
  float* partial = (float*)(ws + OFF_PART);
  float* sums = (float*)(ws + OFF_SUMS);
  ushort* centB = (ushort*)(ws + OFF_CENTB);
  int* gid = (int*)(ws + OFF_GID);
  int* counts = (int*)(ws + OFF_COUNTS);
  float* sumq = (float*)(ws + OFF_SUMQ);
  float* invd = (float*)(ws + OFF_INVD);
  float* losssum = (float*)(ws + OFF_LOSS);

  hipMemsetAsync(ws + ZERO_OFF, 0, ZERO_BYTES, stream);
  k0_gid<<<BN / 1024, 256, 0, stream>>>(subject, labels, gid, counts);
  k1_partial<<<CHUNKS * 8, 256, 0, stream>>>(X, gid, Xb, partial);
  k1b_reduce<<<(KN * DN) / 256, 256, 0, stream>>>(partial, sums);
  k2_cent<<<(KN * DN) / 256, 256, 0, stream>>>(sums, counts, centB);
  k3_dist<<<N2 / 4, 256, 0, stream>>>(Xb, gid, sums, counts, sumq);
  k4_density<<<1, 256, 0, stream>>>(sumq, counts, invd);
  k5_mfma<<<N2 / 128, 256, 0, stream>>>(Xb, centB, subject, labels, invd, losssum);
  k6_final<<<1, 1, 0, stream>>>(losssum, (float*)d_out);
}

// Round 3
// 440.806 us; speedup vs baseline: 1.2794x; 1.0921x over previous
//
#include <hip/hip_runtime.h>
#include <math.h>

// Problem constants
#define BN 32768
#define DN 512
#define SN 32
#define LN 8
#define KN 256
#define N2 65536   // 2*BN
#define CHUNKS 32
#define RPC 1024   // rows per chunk (BN / CHUNKS)

typedef __attribute__((ext_vector_type(8))) short bf16x8;
typedef __attribute__((ext_vector_type(4))) float f32x4;

// workspace layout (byte offsets)
#define OFF_XBF     0ull                      // ushort[N2*DN]      67108864
#define OFF_PART    67108864ull               // float[CHUNKS*KN*DN] 16777216
#define OFF_SUMS    83886080ull               // float[KN*DN]        524288
#define OFF_CENTB   84410368ull               // ushort[KN*DN]       262144
#define OFF_GID     84672512ull               // int[BN]             131072
#define OFF_COUNTS  84803584ull               // int[KN]
#define OFF_SUMQ    84804608ull               // float[KN]
#define OFF_INVD    84805632ull               // float[KN]
#define OFF_LOSS    84806656ull               // float[1]
#define ZERO_OFF    OFF_COUNTS
#define ZERO_BYTES  (84806660ull - OFF_COUNTS)

__device__ __forceinline__ float atomAddF(float* p, float v) {
  return unsafeAtomicAdd(p, v);   // hw global_atomic_add_f32
}

__device__ __forceinline__ ushort f2bf(float x) {
  union { float f; unsigned u; } v; v.f = x;
  unsigned u = v.u;
  unsigned r = (u + 0x7fffu + ((u >> 16) & 1u)) >> 16;  // RNE
  return (ushort)r;
}

__device__ __forceinline__ float bf2f(ushort x) {
  union { unsigned u; float f; } v; v.u = ((unsigned)x) << 16;
  return v.f;
}

// ---- k0: gid + counts histogram ----
__global__ __launch_bounds__(256) void k0_gid(const int* __restrict__ subject,
    const int* __restrict__ labels, int* __restrict__ gid, int* __restrict__ counts) {
  __shared__ int hist[KN];
  hist[threadIdx.x] = 0;
  __syncthreads();
  const int b0 = blockIdx.x * 1024;
  for (int i = threadIdx.x; i < 1024; i += 256) {
    int b = b0 + i;
    int g = subject[b] * LN + labels[b];
    gid[b] = g;
    atomicAdd(&hist[g], 1);
  }
  __syncthreads();
  if (hist[threadIdx.x]) atomicAdd(&counts[threadIdx.x], 2 * hist[threadIdx.x]);
}

// ---- k1: convert X -> bf16 feat layout + per-(chunk,16-dim-slice) group sums ----
// grid: 1024 blocks = 32 row-chunks x 32 dim-slices. LDS 17KB -> 4 blocks/CU.
__global__ __launch_bounds__(256) void k1_partial(const float* __restrict__ X,
    const int* __restrict__ gid, ushort* __restrict__ Xb, float* __restrict__ partial) {
  __shared__ float accs[KN * 17];   // [g][17] padded (16 dims + 1)
  const int slice = blockIdx.x & 31;   // 16 dims each
  const int chunk = blockIdx.x >> 5;   // 1024 rows each
  const int t = threadIdx.x;
  const int lane4 = t & 3;             // float4 within slice
  const int rsub = t >> 2;             // 0..63 rows in flight
  const int d0 = slice * 16;
  for (int j = t; j < KN * 17; j += 256) accs[j] = 0.f;
  __syncthreads();
  const int b0 = chunk * RPC;
#pragma unroll 2
  for (int r0 = 0; r0 < RPC; r0 += 64) {
    const int b = b0 + r0 + rsub;
    const int g = gid[b];
    const float* xp = X + (size_t)b * 1024 + d0 + lane4 * 4;
    float4 x0 = *(const float4*)xp;
    float4 x1 = *(const float4*)(xp + DN);
    ushort4 u0 = {f2bf(x0.x), f2bf(x0.y), f2bf(x0.z), f2bf(x0.w)};
    ushort4 u1 = {f2bf(x1.x), f2bf(x1.y), f2bf(x1.z), f2bf(x1.w)};
    *(ushort4*)(Xb + (size_t)b * DN + d0 + lane4 * 4) = u0;
    *(ushort4*)(Xb + (size_t)(b + BN) * DN + d0 + lane4 * 4) = u1;
    float* ap = &accs[g * 17 + lane4 * 4];
    atomicAdd(ap + 0, x0.x + x1.x);
    atomicAdd(ap + 1, x0.y + x1.y);
    atomicAdd(ap + 2, x0.z + x1.z);
    atomicAdd(ap + 3, x0.w + x1.w);
  }
  __syncthreads();
  for (int j = t; j < KN * 16; j += 256) {
    int g = j >> 4, dl = j & 15;
    partial[(size_t)chunk * (KN * DN) + g * DN + d0 + dl] = accs[g * 17 + dl];
  }
}

// ---- k1b: reduce partials -> sums[g][d] ----
__global__ __launch_bounds__(256) void k1b_reduce(const float* __restrict__ partial,
    float* __restrict__ sums) {
  const int i = blockIdx.x * 256 + threadIdx.x;   // over KN*DN
  float s = 0.f;
#pragma unroll
  for (int c = 0; c < CHUNKS; ++c) s += partial[(size_t)c * (KN * DN) + i];
  sums[i] = s;
}

// ---- k2: bf16 centroids cent[g][d] ----
__global__ __launch_bounds__(256) void k2_cent(const float* __restrict__ sums,
    const int* __restrict__ counts, ushort* __restrict__ centB) {
  const int i = blockIdx.x * 256 + threadIdx.x;   // [g][d]
  const int g = i >> 9;
  centB[i] = f2bf(sums[i] / (float)counts[g]);
}

// ---- k3: per-row distance^0.25 accumulation (reads bf16 X copy) ----
__global__ __launch_bounds__(256) void k3_dist(const ushort* __restrict__ Xb,
    const int* __restrict__ gid, const float* __restrict__ sums,
    const int* __restrict__ counts, float* __restrict__ sumq) {
  const int row = blockIdx.x * 4 + (threadIdx.x >> 6);
  const int lane = threadIdx.x & 63;
  const int b = row & (BN - 1);
  const int g = gid[b];
  const float invc = 1.0f / (float)counts[g];
  int4 chunk = *(const int4*)(Xb + (size_t)row * DN + lane * 8);
  const ushort* us = (const ushort*)&chunk;
  const float* s = sums + g * DN + lane * 8;
  float4 s0 = *(const float4*)s;
  float4 s1 = *(const float4*)(s + 4);
  float cs[8] = {s0.x, s0.y, s0.z, s0.w, s1.x, s1.y, s1.z, s1.w};
  float ss = 0.f;
#pragma unroll
  for (int k = 0; k < 8; ++k) {
    float diff = bf2f(us[k]) - cs[k] * invc;
    ss += diff * diff;
  }
#pragma unroll
  for (int off = 32; off > 0; off >>= 1) ss += __shfl_down(ss, off, 64);
  if (lane == 0) atomAddF(&sumq[g], sqrtf(sqrtf(ss)));
}

// ---- k4: density -> invd ----
__global__ __launch_bounds__(256) void k4_density(const float* __restrict__ sumq,
    const int* __restrict__ counts, float* __restrict__ invd) {
  __shared__ float sv[256];
  __shared__ float st[256];
  const int t = threadIdx.x;
  const int cnt = counts[t];
  const bool valid = cnt > 1;
  float dens = 0.f;
  if (valid) dens = (sumq[t] / (float)cnt) / logf((float)cnt + 10.f);
  sv[t] = valid ? dens : -INFINITY;
  __syncthreads();
  for (int s = 128; s > 0; s >>= 1) {
    if (t < s) sv[t] = fmaxf(sv[t], sv[t + s]);
    __syncthreads();
  }
  const float dmax = sv[0];
  __syncthreads();
  const float d0 = valid ? dens : dmax;
  sv[t] = d0;
  __syncthreads();
  int rank = 0;
  for (int j = 0; j < 256; ++j) {
    float vj = sv[j];
    rank += (vj < d0) || (vj == d0 && j < t);
  }
  st[rank] = d0;
  __syncthreads();
  const float q10 = 0.5f * (st[25] + st[26]);
  const float q90 = 0.5f * (st[229] + st[230]);
  const float dc = fminf(fmaxf(d0, q10), q90);
  sv[t] = dc;
  __syncthreads();
  for (int s = 128; s > 0; s >>= 1) {
    if (t < s) sv[t] += sv[t + s];
    __syncthreads();
  }
  const float mean = sv[0] * (1.0f / 256.f);
  invd[t] = mean / (0.1f * dc);
}

// ---- k5: MFMA GEMM (128 rows x 256 groups, K=512) + fused softmax loss ----
#define ARS 144   // A row stride bytes (64 bf16 + 8 pad)
#define BRS 144
__global__ __launch_bounds__(256, 2) void k5_mfma(const ushort* __restrict__ Xb,
    const ushort* __restrict__ centB, const int* __restrict__ subject,
    const int* __restrict__ labels, const float* __restrict__ invd,
    float* __restrict__ losssum) {
  __shared__ char smem[128 * ARS + 256 * BRS + 1024];
  char* ldsA = smem;                 // [128][144B]
  char* ldsB = smem + 128 * ARS;     // [256][144B]
  float* maxbuf = (float*)smem;      // epilogue aliases ldsA: [4][128]
  float* gmax = (float*)(smem + 2048);    // [128]
  float* ebuf = (float*)(smem + 2560);    // [4][128]
  float* zbuf = (float*)(smem + 4608);    // [4][128]
  int* labs = (int*)(smem + 128 * ARS + 256 * BRS);
  int* subs = labs + 128;

  const int t = threadIdx.x;
  const int w = t >> 6;
  const int lane = t & 63;
  const int quad = lane >> 4;
  const int n16 = lane & 15;
  const int rowbase = blockIdx.x * 128;

  if (t < 128) {
    int b = (rowbase + t) & (BN - 1);
    labs[t] = labels[b];
    subs[t] = subject[b];
  }

  f32x4 acc[8][4];
#pragma unroll
  for (int mt = 0; mt < 8; ++mt)
#pragma unroll
    for (int nt = 0; nt < 4; ++nt) acc[mt][nt] = (f32x4){0.f, 0.f, 0.f, 0.f};

  const ushort* Arow = Xb + (size_t)rowbase * DN;

  for (int k0 = 0; k0 < DN; k0 += 64) {
    __syncthreads();
#pragma unroll
    for (int i = 0; i < 4; ++i) {
      int j = t + i * 256;
      int r = j >> 3, c = j & 7;
      *(int4*)(ldsA + r * ARS + c * 16) =
          *(const int4*)(Arow + (size_t)r * DN + k0 + c * 8);
    }
#pragma unroll
    for (int i = 0; i < 8; ++i) {
      int j = t + i * 256;
      int g = j >> 3, c = j & 7;
      *(int4*)(ldsB + g * BRS + c * 16) =
          *(const int4*)(centB + (size_t)g * DN + k0 + c * 8);
    }
    __syncthreads();
#pragma unroll
    for (int s = 0; s < 2; ++s) {
      bf16x8 bfr[4];
#pragma unroll
      for (int nt = 0; nt < 4; ++nt) {
        int g = w * 64 + nt * 16 + n16;
        bfr[nt] = *(bf16x8*)(ldsB + g * BRS + s * 64 + quad * 16);
      }
#pragma unroll
      for (int mt = 0; mt < 8; ++mt) {
        bf16x8 afr = *(bf16x8*)(ldsA + (mt * 16 + n16) * ARS + s * 64 + quad * 16);
#pragma unroll
        for (int nt = 0; nt < 4; ++nt)
          acc[mt][nt] = __builtin_amdgcn_mfma_f32_16x16x32_bf16(afr, bfr[nt], acc[mt][nt], 0, 0, 0);
      }
    }
  }

  float iv[4];
#pragma unroll
  for (int nt = 0; nt < 4; ++nt) iv[nt] = invd[w * 64 + nt * 16 + n16];

  __syncthreads();

#pragma unroll
  for (int mt = 0; mt < 8; ++mt) {
#pragma unroll
    for (int r = 0; r < 4; ++r) {
      float mm = -INFINITY;
#pragma unroll
      for (int nt = 0; nt < 4; ++nt) mm = fmaxf(mm, acc[mt][nt][r] * iv[nt]);
#pragma unroll
      for (int off = 1; off < 16; off <<= 1) mm = fmaxf(mm, __shfl_xor(mm, off, 64));
      if (n16 == 0) maxbuf[w * 128 + mt * 16 + quad * 4 + r] = mm;
    }
  }
  __syncthreads();
  if (t < 128)
    gmax[t] = fmaxf(fmaxf(maxbuf[t], maxbuf[128 + t]),
                    fmaxf(maxbuf[256 + t], maxbuf[384 + t]));
  __syncthreads();

#pragma unroll
  for (int mt = 0; mt < 8; ++mt) {
#pragma unroll
    for (int r = 0; r < 4; ++r) {
      const int row = mt * 16 + quad * 4 + r;
      const float gm = gmax[row];
      const int lab = labs[row];
      const int sub = subs[row];
      float e = 0.f, z = 0.f;
      if ((n16 & 7) == lab) {
#pragma unroll
        for (int nt = 0; nt < 4; ++nt) {
          int gdiv8 = w * 8 + nt * 2 + (n16 >> 3);
          if (gdiv8 != sub) {
            float sv = acc[mt][nt][r] * iv[nt] - gm;
            e += expf(sv);
            z += sv;
          }
        }
      }
#pragma unroll
      for (int off = 1; off < 16; off <<= 1) {
        e += __shfl_xor(e, off, 64);
        z += __shfl_xor(z, off, 64);
      }
      if (n16 == 0) {
        ebuf[w * 128 + row] = e;
        zbuf[w * 128 + row] = z;
      }
    }
  }
  __syncthreads();

  float lsum = 0.f;
  if (t < 128) {
    float e = ebuf[t] + ebuf[128 + t] + ebuf[256 + t] + ebuf[384 + t];
    float z = zbuf[t] + zbuf[128 + t] + zbuf[256 + t] + zbuf[384 + t];
    lsum = logf(225.f + e) - z * (1.0f / 31.0f);
  }
#pragma unroll
  for (int off = 32; off > 0; off >>= 1) lsum += __shfl_down(lsum, off, 64);
  if (lane == 0 && lsum != 0.f) atomAddF(losssum, lsum);
}

// ---- k6: final mean ----
__global__ void k6_final(const float* __restrict__ losssum, float* __restrict__ out) {
  out[0] = losssum[0] * (1.0f / (float)N2);
}

extern "C" void kernel_launch(void* const* d_in, const int* in_sizes, int n_in,
                              void* d_out, int out_size, void* d_ws, size_t ws_size,
                              hipStream_t stream) {
  const float* X = (const float*)d_in[0];
  const int* subject = (const int*)d_in[1];
  const int* labels = (const int*)d_in[2];
  char* ws = (char*)d_ws;
  ushort* Xb = (ushort*)(ws + OFF_XBF);
  float* partial = (float*)(ws + OFF_PART);
  float* sums = (float*)(ws + OFF_SUMS);
  ushort* centB = (ushort*)(ws + OFF_CENTB);
  int* gid = (int*)(ws + OFF_GID);
  int* counts = (int*)(ws + OFF_COUNTS);
  float* sumq = (float*)(ws + OFF_SUMQ);
  float* invd = (float*)(ws + OFF_INVD);
  float* losssum = (float*)(ws + OFF_LOSS);

  hipMemsetAsync(ws + ZERO_OFF, 0, ZERO_BYTES, stream);
  k0_gid<<<BN / 1024, 256, 0, stream>>>(subject, labels, gid, counts);
  k1_partial<<<CHUNKS * 32, 256, 0, stream>>>(X, gid, Xb, partial);
  k1b_reduce<<<(KN * DN) / 256, 256, 0, stream>>>(partial, sums);
  k2_cent<<<(KN * DN) / 256, 256, 0, stream>>>(sums, counts, centB);
  k3_dist<<<N2 / 4, 256, 0, stream>>>(Xb, gid, sums, counts, sumq);
  k4_density<<<1, 256, 0, stream>>>(sumq, counts, invd);
  k5_mfma<<<N2 / 128, 256, 0, stream>>>(Xb, centB, subject, labels, invd, losssum);
  k6_final<<<1, 1, 0, stream>>>(losssum, (float*)d_out);
}

// Round 4
// 402.723 us; speedup vs baseline: 1.4004x; 1.0946x over previous
//
#include <hip/hip_runtime.h>
#include <math.h>

// Problem constants
#define BN 32768
#define DN 512
#define SN 32
#define LN 8
#define KN 256
#define N2 65536   // 2*BN
#define SPLIT 8    // blocks per group in k1

typedef __attribute__((ext_vector_type(8))) short bf16x8;
typedef __attribute__((ext_vector_type(4))) float f32x4;

// workspace layout (byte offsets)
#define OFF_XBF     0ull            // ushort[N2*DN]            67108864
#define OFF_PART    67108864ull     // float[SPLIT*KN*DN]        4194304
#define OFF_SUMS    71303168ull     // float[KN*DN]               524288
#define OFF_CENTB   71827456ull     // ushort[KN*DN]              262144
#define OFF_GID     72089600ull     // int[BN]                    131072
#define OFF_PERM    72220672ull     // int[BN]                    131072
#define OFF_BASE    72351744ull     // int[KN+1]
#define OFF_OFFW    72352772ull     // int[KN]
#define OFF_COUNTS  72353796ull     // int[KN]
#define OFF_SUMQ    72354820ull     // float[KN]
#define OFF_INVD    72355844ull     // float[KN]
#define OFF_LOSS    72356868ull     // float[1]
#define ZERO_OFF    OFF_COUNTS
#define ZERO_BYTES  (72356872ull - OFF_COUNTS)

__device__ __forceinline__ float atomAddF(float* p, float v) {
  return unsafeAtomicAdd(p, v);   // hw global_atomic_add_f32
}

__device__ __forceinline__ ushort f2bf(float x) {
  union { float f; unsigned u; } v; v.f = x;
  unsigned u = v.u;
  unsigned r = (u + 0x7fffu + ((u >> 16) & 1u)) >> 16;  // RNE
  return (ushort)r;
}

__device__ __forceinline__ float bf2f(ushort x) {
  union { unsigned u; float f; } v; v.u = ((unsigned)x) << 16;
  return v.f;
}

// ---- k0a: gid + counts histogram ----
__global__ __launch_bounds__(256) void k0_gid(const int* __restrict__ subject,
    const int* __restrict__ labels, int* __restrict__ gid, int* __restrict__ counts) {
  __shared__ int hist[KN];
  hist[threadIdx.x] = 0;
  __syncthreads();
  const int b0 = blockIdx.x * 1024;
  for (int i = threadIdx.x; i < 1024; i += 256) {
    int b = b0 + i;
    int g = subject[b] * LN + labels[b];
    gid[b] = g;
    atomicAdd(&hist[g], 1);
  }
  __syncthreads();
  if (hist[threadIdx.x]) atomicAdd(&counts[threadIdx.x], 2 * hist[threadIdx.x]);
}

// ---- k0b: exclusive scan of per-group row counts -> base, offw ----
__global__ __launch_bounds__(256) void k0b_scan(const int* __restrict__ counts,
    int* __restrict__ base, int* __restrict__ offw) {
  __shared__ int sh[KN];
  const int t = threadIdx.x;
  const int h = counts[t] >> 1;   // rows (not x2 views)
  sh[t] = h;
  __syncthreads();
  for (int d = 1; d < 256; d <<= 1) {
    int add = (t >= d) ? sh[t - d] : 0;
    __syncthreads();
    sh[t] += add;
    __syncthreads();
  }
  const int excl = sh[t] - h;
  base[t] = excl;
  offw[t] = excl;
  if (t == 255) base[256] = sh[255];
}

// ---- k0c: counting-sort scatter -> perm ----
__global__ __launch_bounds__(256) void k0c_scatter(const int* __restrict__ gid,
    int* __restrict__ offw, int* __restrict__ perm) {
  const int b = blockIdx.x * 256 + threadIdx.x;
  const int g = gid[b];
  const int pos = atomicAdd(&offw[g], 1);
  perm[pos] = b;
}

// ---- k1: sorted segment-reduce group sums + f32->bf16 conversion ----
// grid: 256 groups x 8 splits. Block streams whole 4KB rows, register acc.
__global__ __launch_bounds__(256) void k1_sums(const float* __restrict__ X,
    const int* __restrict__ perm, const int* __restrict__ base,
    ushort* __restrict__ Xb, float* __restrict__ partial) {
  __shared__ float buf[512];
  const int g = blockIdx.x >> 3;
  const int s = blockIdx.x & (SPLIT - 1);
  const int t = threadIdx.x;
  const int start = base[g], end = base[g + 1];

  float4 acc = {0.f, 0.f, 0.f, 0.f};
  int i = start + s;
  if (i < end) {
    int idx = perm[i];
    float4 x = *(const float4*)(X + (size_t)idx * 1024 + t * 4);
    while (true) {
      const int inext = i + SPLIT;
      int idxn = idx;
      float4 xn = x;
      if (inext < end) {
        idxn = perm[inext];
        xn = *(const float4*)(X + (size_t)idxn * 1024 + t * 4);
      }
      acc.x += x.x; acc.y += x.y; acc.z += x.z; acc.w += x.w;
      ushort4 u = {f2bf(x.x), f2bf(x.y), f2bf(x.z), f2bf(x.w)};
      const size_t dst = (t < 128) ? ((size_t)idx * DN + t * 4)
                                   : ((size_t)(idx + BN) * DN + (t - 128) * 4);
      *(ushort4*)(Xb + dst) = u;
      if (inext >= end) break;
      i = inext; idx = idxn; x = xn;
    }
  }
  // fold view-1 dims (threads 128..255) onto view-0 dims
  if (t >= 128) *(float4*)&buf[(t - 128) * 4] = acc;
  __syncthreads();
  if (t < 128) {
    float4 o = *(float4*)&buf[t * 4];
    float4 out = {acc.x + o.x, acc.y + o.y, acc.z + o.z, acc.w + o.w};
    *(float4*)&partial[((size_t)s * KN + g) * DN + t * 4] = out;
  }
}

// ---- k1b: reduce split partials -> sums + bf16 centroids (fused k2) ----
__global__ __launch_bounds__(256) void k1b_cent(const float* __restrict__ partial,
    const int* __restrict__ counts, float* __restrict__ sums,
    ushort* __restrict__ centB) {
  const int i = blockIdx.x * 256 + threadIdx.x;   // over KN*DN, [g][d]
  const int g = i >> 9;
  float ss = 0.f;
#pragma unroll
  for (int s = 0; s < SPLIT; ++s) ss += partial[(size_t)s * (KN * DN) + i];
  sums[i] = ss;
  centB[i] = f2bf(ss / (float)counts[g]);
}

// ---- k3: per-row distance^0.25 accumulation (reads bf16 X copy) ----
__global__ __launch_bounds__(256) void k3_dist(const ushort* __restrict__ Xb,
    const int* __restrict__ gid, const float* __restrict__ sums,
    const int* __restrict__ counts, float* __restrict__ sumq) {
  const int row = blockIdx.x * 4 + (threadIdx.x >> 6);
  const int lane = threadIdx.x & 63;
  const int b = row & (BN - 1);
  const int g = gid[b];
  const float invc = 1.0f / (float)counts[g];
  int4 chunk = *(const int4*)(Xb + (size_t)row * DN + lane * 8);
  const ushort* us = (const ushort*)&chunk;
  const float* s = sums + g * DN + lane * 8;
  float4 s0 = *(const float4*)s;
  float4 s1 = *(const float4*)(s + 4);
  float cs[8] = {s0.x, s0.y, s0.z, s0.w, s1.x, s1.y, s1.z, s1.w};
  float ss = 0.f;
#pragma unroll
  for (int k = 0; k < 8; ++k) {
    float diff = bf2f(us[k]) - cs[k] * invc;
    ss += diff * diff;
  }
#pragma unroll
  for (int off = 32; off > 0; off >>= 1) ss += __shfl_down(ss, off, 64);
  if (lane == 0) atomAddF(&sumq[g], sqrtf(sqrtf(ss)));
}

// ---- k4: density -> invd ----
__global__ __launch_bounds__(256) void k4_density(const float* __restrict__ sumq,
    const int* __restrict__ counts, float* __restrict__ invd) {
  __shared__ float sv[256];
  __shared__ float st[256];
  const int t = threadIdx.x;
  const int cnt = counts[t];
  const bool valid = cnt > 1;
  float dens = 0.f;
  if (valid) dens = (sumq[t] / (float)cnt) / logf((float)cnt + 10.f);
  sv[t] = valid ? dens : -INFINITY;
  __syncthreads();
  for (int s = 128; s > 0; s >>= 1) {
    if (t < s) sv[t] = fmaxf(sv[t], sv[t + s]);
    __syncthreads();
  }
  const float dmax = sv[0];
  __syncthreads();
  const float d0 = valid ? dens : dmax;
  sv[t] = d0;
  __syncthreads();
  int rank = 0;
  for (int j = 0; j < 256; ++j) {
    float vj = sv[j];
    rank += (vj < d0) || (vj == d0 && j < t);
  }
  st[rank] = d0;
  __syncthreads();
  const float q10 = 0.5f * (st[25] + st[26]);
  const float q90 = 0.5f * (st[229] + st[230]);
  const float dc = fminf(fmaxf(d0, q10), q90);
  sv[t] = dc;
  __syncthreads();
  for (int s = 128; s > 0; s >>= 1) {
    if (t < s) sv[t] += sv[t + s];
    __syncthreads();
  }
  const float mean = sv[0] * (1.0f / 256.f);
  invd[t] = mean / (0.1f * dc);
}

// ---- k5: MFMA GEMM (128 rows x 256 groups, K=512) + fused softmax loss ----
#define ARS 144   // A row stride bytes (64 bf16 + 8 pad)
#define BRS 144
__global__ __launch_bounds__(256, 2) void k5_mfma(const ushort* __restrict__ Xb,
    const ushort* __restrict__ centB, const int* __restrict__ subject,
    const int* __restrict__ labels, const float* __restrict__ invd,
    float* __restrict__ losssum) {
  __shared__ char smem[128 * ARS + 256 * BRS + 1024];
  char* ldsA = smem;                 // [128][144B]
  char* ldsB = smem + 128 * ARS;     // [256][144B]
  float* maxbuf = (float*)smem;      // epilogue aliases ldsA: [4][128]
  float* gmax = (float*)(smem + 2048);    // [128]
  float* ebuf = (float*)(smem + 2560);    // [4][128]
  float* zbuf = (float*)(smem + 4608);    // [4][128]
  int* labs = (int*)(smem + 128 * ARS + 256 * BRS);
  int* subs = labs + 128;

  const int t = threadIdx.x;
  const int w = t >> 6;
  const int lane = t & 63;
  const int quad = lane >> 4;
  const int n16 = lane & 15;
  const int rowbase = blockIdx.x * 128;

  if (t < 128) {
    int b = (rowbase + t) & (BN - 1);
    labs[t] = labels[b];
    subs[t] = subject[b];
  }

  f32x4 acc[8][4];
#pragma unroll
  for (int mt = 0; mt < 8; ++mt)
#pragma unroll
    for (int nt = 0; nt < 4; ++nt) acc[mt][nt] = (f32x4){0.f, 0.f, 0.f, 0.f};

  const ushort* Arow = Xb + (size_t)rowbase * DN;

  for (int k0 = 0; k0 < DN; k0 += 64) {
    __syncthreads();
#pragma unroll
    for (int i = 0; i < 4; ++i) {
      int j = t + i * 256;
      int r = j >> 3, c = j & 7;
      *(int4*)(ldsA + r * ARS + c * 16) =
          *(const int4*)(Arow + (size_t)r * DN + k0 + c * 8);
    }
#pragma unroll
    for (int i = 0; i < 8; ++i) {
      int j = t + i * 256;
      int g = j >> 3, c = j & 7;
      *(int4*)(ldsB + g * BRS + c * 16) =
          *(const int4*)(centB + (size_t)g * DN + k0 + c * 8);
    }
    __syncthreads();
#pragma unroll
    for (int s = 0; s < 2; ++s) {
      bf16x8 bfr[4];
#pragma unroll
      for (int nt = 0; nt < 4; ++nt) {
        int g = w * 64 + nt * 16 + n16;
        bfr[nt] = *(bf16x8*)(ldsB + g * BRS + s * 64 + quad * 16);
      }
#pragma unroll
      for (int mt = 0; mt < 8; ++mt) {
        bf16x8 afr = *(bf16x8*)(ldsA + (mt * 16 + n16) * ARS + s * 64 + quad * 16);
#pragma unroll
        for (int nt = 0; nt < 4; ++nt)
          acc[mt][nt] = __builtin_amdgcn_mfma_f32_16x16x32_bf16(afr, bfr[nt], acc[mt][nt], 0, 0, 0);
      }
    }
  }

  float iv[4];
#pragma unroll
  for (int nt = 0; nt < 4; ++nt) iv[nt] = invd[w * 64 + nt * 16 + n16];

  __syncthreads();

#pragma unroll
  for (int mt = 0; mt < 8; ++mt) {
#pragma unroll
    for (int r = 0; r < 4; ++r) {
      float mm = -INFINITY;
#pragma unroll
      for (int nt = 0; nt < 4; ++nt) mm = fmaxf(mm, acc[mt][nt][r] * iv[nt]);
#pragma unroll
      for (int off = 1; off < 16; off <<= 1) mm = fmaxf(mm, __shfl_xor(mm, off, 64));
      if (n16 == 0) maxbuf[w * 128 + mt * 16 + quad * 4 + r] = mm;
    }
  }
  __syncthreads();
  if (t < 128)
    gmax[t] = fmaxf(fmaxf(maxbuf[t], maxbuf[128 + t]),
                    fmaxf(maxbuf[256 + t], maxbuf[384 + t]));
  __syncthreads();

#pragma unroll
  for (int mt = 0; mt < 8; ++mt) {
#pragma unroll
    for (int r = 0; r < 4; ++r) {
      const int row = mt * 16 + quad * 4 + r;
      const float gm = gmax[row];
      const int lab = labs[row];
      const int sub = subs[row];
      float e = 0.f, z = 0.f;
      if ((n16 & 7) == lab) {
#pragma unroll
        for (int nt = 0; nt < 4; ++nt) {
          int gdiv8 = w * 8 + nt * 2 + (n16 >> 3);
          if (gdiv8 != sub) {
            float sv = acc[mt][nt][r] * iv[nt] - gm;
            e += expf(sv);
            z += sv;
          }
        }
      }
#pragma unroll
      for (int off = 1; off < 16; off <<= 1) {
        e += __shfl_xor(e, off, 64);
        z += __shfl_xor(z, off, 64);
      }
      if (n16 == 0) {
        ebuf[w * 128 + row] = e;
        zbuf[w * 128 + row] = z;
      }
    }
  }
  __syncthreads();

  float lsum = 0.f;
  if (t < 128) {
    float e = ebuf[t] + ebuf[128 + t] + ebuf[256 + t] + ebuf[384 + t];
    float z = zbuf[t] + zbuf[128 + t] + zbuf[256 + t] + zbuf[384 + t];
    lsum = logf(225.f + e) - z * (1.0f / 31.0f);
  }
#pragma unroll
  for (int off = 32; off > 0; off >>= 1) lsum += __shfl_down(lsum, off, 64);
  if (lane == 0 && lsum != 0.f) atomAddF(losssum, lsum);
}

// ---- k6: final mean ----
__global__ void k6_final(const float* __restrict__ losssum, float* __restrict__ out) {
  out[0] = losssum[0] * (1.0f / (float)N2);
}

extern "C" void kernel_launch(void* const* d_in, const int* in_sizes, int n_in,
                              void* d_out, int out_size, void* d_ws, size_t ws_size,
                              hipStream_t stream) {
  const float* X = (const float*)d_in[0];
  const int* subject = (const int*)d_in[1];
  const int* labels = (const int*)d_in[2];
  char* ws = (char*)d_ws;
  ushort* Xb = (ushort*)(ws + OFF_XBF);
  float* partial = (float*)(ws + OFF_PART);
  float* sums = (float*)(ws + OFF_SUMS);
  ushort* centB = (ushort*)(ws + OFF_CENTB);
  int* gid = (int*)(ws + OFF_GID);
  int* perm = (int*)(ws + OFF_PERM);
  int* basep = (int*)(ws + OFF_BASE);
  int* offw = (int*)(ws + OFF_OFFW);
  int* counts = (int*)(ws + OFF_COUNTS);
  float* sumq = (float*)(ws + OFF_SUMQ);
  float* invd = (float*)(ws + OFF_INVD);
  float* losssum = (float*)(ws + OFF_LOSS);

  hipMemsetAsync(ws + ZERO_OFF, 0, ZERO_BYTES, stream);
  k0_gid<<<BN / 1024, 256, 0, stream>>>(subject, labels, gid, counts);
  k0b_scan<<<1, 256, 0, stream>>>(counts, basep, offw);
  k0c_scatter<<<BN / 256, 256, 0, stream>>>(gid, offw, perm);
  k1_sums<<<KN * SPLIT, 256, 0, stream>>>(X, perm, basep, Xb, partial);
  k1b_cent<<<(KN * DN) / 256, 256, 0, stream>>>(partial, counts, sums, centB);
  k3_dist<<<N2 / 4, 256, 0, stream>>>(Xb, gid, sums, counts, sumq);
  k4_density<<<1, 256, 0, stream>>>(sumq, counts, invd);
  k5_mfma<<<N2 / 128, 256, 0, stream>>>(Xb, centB, subject, labels, invd, losssum);
  k6_final<<<1, 1, 0, stream>>>(losssum, (float*)d_out);
}

// Round 5
// 314.148 us; speedup vs baseline: 1.7952x; 1.2820x over previous
//
#include <hip/hip_runtime.h>
#include <math.h>

// Problem constants
#define BN 32768
#define DN 512
#define SN 32
#define LN 8
#define KN 256
#define N2 65536   // 2*BN
#define SPLIT 8    // blocks per group in k1/k3

typedef __attribute__((ext_vector_type(8))) short bf16x8;
typedef __attribute__((ext_vector_type(4))) float f32x4;

// workspace layout (byte offsets)
#define OFF_XBF     0ull            // ushort[N2*DN]            67108864
#define OFF_PART    67108864ull     // float[SPLIT*KN*DN]        4194304
#define OFF_SUMS    71303168ull     // float[KN*DN]               524288
#define OFF_CENTB   71827456ull     // ushort[KN*DN]              262144
#define OFF_GID     72089600ull     // int[BN]                    131072
#define OFF_PERM    72220672ull     // int[BN]                    131072
#define OFF_BASE    72351744ull     // int[KN+1]
#define OFF_OFFW    72352772ull     // int[KN]
#define OFF_COUNTS  72353796ull     // int[KN]
#define OFF_SUMQ    72354820ull     // float[KN]
#define OFF_INVD    72355844ull     // float[KN]
#define OFF_LOSS    72356868ull     // float[1]
#define ZERO_OFF    OFF_COUNTS
#define ZERO_BYTES  (72356872ull - OFF_COUNTS)

__device__ __forceinline__ float atomAddF(float* p, float v) {
  return unsafeAtomicAdd(p, v);   // hw global_atomic_add_f32
}

__device__ __forceinline__ ushort f2bf(float x) {
  union { float f; unsigned u; } v; v.f = x;
  unsigned u = v.u;
  unsigned r = (u + 0x7fffu + ((u >> 16) & 1u)) >> 16;  // RNE
  return (ushort)r;
}

__device__ __forceinline__ float bf2f(ushort x) {
  union { unsigned u; float f; } v; v.u = ((unsigned)x) << 16;
  return v.f;
}

// ---- k0a: gid + counts histogram ----
__global__ __launch_bounds__(256) void k0_gid(const int* __restrict__ subject,
    const int* __restrict__ labels, int* __restrict__ gid, int* __restrict__ counts) {
  __shared__ int hist[KN];
  hist[threadIdx.x] = 0;
  __syncthreads();
  const int b0 = blockIdx.x * 1024;
  for (int i = threadIdx.x; i < 1024; i += 256) {
    int b = b0 + i;
    int g = subject[b] * LN + labels[b];
    gid[b] = g;
    atomicAdd(&hist[g], 1);
  }
  __syncthreads();
  if (hist[threadIdx.x]) atomicAdd(&counts[threadIdx.x], 2 * hist[threadIdx.x]);
}

// ---- k0b: exclusive scan of per-group row counts -> base, offw ----
__global__ __launch_bounds__(256) void k0b_scan(const int* __restrict__ counts,
    int* __restrict__ base, int* __restrict__ offw) {
  __shared__ int sh[KN];
  const int t = threadIdx.x;
  const int h = counts[t] >> 1;   // rows (not x2 views)
  sh[t] = h;
  __syncthreads();
  for (int d = 1; d < 256; d <<= 1) {
    int add = (t >= d) ? sh[t - d] : 0;
    __syncthreads();
    sh[t] += add;
    __syncthreads();
  }
  const int excl = sh[t] - h;
  base[t] = excl;
  offw[t] = excl;
  if (t == 255) base[256] = sh[255];
}

// ---- k0c: counting-sort scatter -> perm ----
__global__ __launch_bounds__(256) void k0c_scatter(const int* __restrict__ gid,
    int* __restrict__ offw, int* __restrict__ perm) {
  const int b = blockIdx.x * 256 + threadIdx.x;
  const int g = gid[b];
  const int pos = atomicAdd(&offw[g], 1);
  perm[pos] = b;
}

// ---- k1: sorted segment-reduce group sums + f32->bf16 conversion ----
__global__ __launch_bounds__(256) void k1_sums(const float* __restrict__ X,
    const int* __restrict__ perm, const int* __restrict__ base,
    ushort* __restrict__ Xb, float* __restrict__ partial) {
  __shared__ float buf[512];
  const int g = blockIdx.x >> 3;
  const int s = blockIdx.x & (SPLIT - 1);
  const int t = threadIdx.x;
  const int start = base[g], end = base[g + 1];

  float4 acc = {0.f, 0.f, 0.f, 0.f};
  int i = start + s;
  if (i < end) {
    int idx = perm[i];
    float4 x = *(const float4*)(X + (size_t)idx * 1024 + t * 4);
    while (true) {
      const int inext = i + SPLIT;
      int idxn = idx;
      float4 xn = x;
      if (inext < end) {
        idxn = perm[inext];
        xn = *(const float4*)(X + (size_t)idxn * 1024 + t * 4);
      }
      acc.x += x.x; acc.y += x.y; acc.z += x.z; acc.w += x.w;
      ushort4 u = {f2bf(x.x), f2bf(x.y), f2bf(x.z), f2bf(x.w)};
      const size_t dst = (t < 128) ? ((size_t)idx * DN + t * 4)
                                   : ((size_t)(idx + BN) * DN + (t - 128) * 4);
      *(ushort4*)(Xb + dst) = u;
      if (inext >= end) break;
      i = inext; idx = idxn; x = xn;
    }
  }
  if (t >= 128) *(float4*)&buf[(t - 128) * 4] = acc;
  __syncthreads();
  if (t < 128) {
    float4 o = *(float4*)&buf[t * 4];
    float4 out = {acc.x + o.x, acc.y + o.y, acc.z + o.z, acc.w + o.w};
    *(float4*)&partial[((size_t)s * KN + g) * DN + t * 4] = out;
  }
}

// ---- k1b: reduce split partials -> sums + bf16 centroids ----
__global__ __launch_bounds__(256) void k1b_cent(const float* __restrict__ partial,
    const int* __restrict__ counts, float* __restrict__ sums,
    ushort* __restrict__ centB) {
  const int i = blockIdx.x * 256 + threadIdx.x;   // over KN*DN, [g][d]
  const int g = i >> 9;
  float ss = 0.f;
#pragma unroll
  for (int s = 0; s < SPLIT; ++s) ss += partial[(size_t)s * (KN * DN) + i];
  sums[i] = ss;
  centB[i] = f2bf(ss / (float)counts[g]);
}

// ---- k3: group-per-block distance^0.25 accumulation, 1 atomic/block ----
// grid: 256 groups x 8 splits; wave-per-row-view inner loop; centroid in regs.
__global__ __launch_bounds__(256) void k3_dist(const ushort* __restrict__ Xb,
    const int* __restrict__ perm, const int* __restrict__ base,
    const float* __restrict__ sums, const int* __restrict__ counts,
    float* __restrict__ sumq) {
  __shared__ float wacc[4];
  const int g = blockIdx.x >> 3;
  const int s = blockIdx.x & (SPLIT - 1);
  const int t = threadIdx.x;
  const int w = t >> 6;
  const int lane = t & 63;
  const int start = base[g], end = base[g + 1];
  const int nviews = 2 * (end - start);
  const float invc = 1.0f / (float)counts[g];
  const float* sp = sums + g * DN + lane * 8;
  float4 c0 = *(const float4*)sp;
  float4 c1 = *(const float4*)(sp + 4);
  const float cs[8] = {c0.x * invc, c0.y * invc, c0.z * invc, c0.w * invc,
                       c1.x * invc, c1.y * invc, c1.z * invc, c1.w * invc};
  float q = 0.f;
  const int vs = s * 4 + w;   // virtual split 0..31
  for (int j = vs; j < nviews; j += SPLIT * 4) {
    const int idx = perm[start + (j >> 1)];
    const int row = idx + (j & 1) * BN;
    int4 chunk = *(const int4*)(Xb + (size_t)row * DN + lane * 8);
    const ushort* us = (const ushort*)&chunk;
    float ss = 0.f;
#pragma unroll
    for (int k = 0; k < 8; ++k) {
      float diff = bf2f(us[k]) - cs[k];
      ss += diff * diff;
    }
#pragma unroll
    for (int off = 32; off > 0; off >>= 1) ss += __shfl_down(ss, off, 64);
    if (lane == 0) q += sqrtf(sqrtf(ss));
  }
  if (lane == 0) wacc[w] = q;
  __syncthreads();
  if (t == 0) atomAddF(&sumq[g], wacc[0] + wacc[1] + wacc[2] + wacc[3]);
}

// ---- k4: density -> invd ----
__global__ __launch_bounds__(256) void k4_density(const float* __restrict__ sumq,
    const int* __restrict__ counts, float* __restrict__ invd) {
  __shared__ float sv[256];
  __shared__ float st[256];
  const int t = threadIdx.x;
  const int cnt = counts[t];
  const bool valid = cnt > 1;
  float dens = 0.f;
  if (valid) dens = (sumq[t] / (float)cnt) / logf((float)cnt + 10.f);
  sv[t] = valid ? dens : -INFINITY;
  __syncthreads();
  for (int s = 128; s > 0; s >>= 1) {
    if (t < s) sv[t] = fmaxf(sv[t], sv[t + s]);
    __syncthreads();
  }
  const float dmax = sv[0];
  __syncthreads();
  const float d0 = valid ? dens : dmax;
  sv[t] = d0;
  __syncthreads();
  int rank = 0;
  for (int j = 0; j < 256; ++j) {
    float vj = sv[j];
    rank += (vj < d0) || (vj == d0 && j < t);
  }
  st[rank] = d0;
  __syncthreads();
  const float q10 = 0.5f * (st[25] + st[26]);
  const float q90 = 0.5f * (st[229] + st[230]);
  const float dc = fminf(fmaxf(d0, q10), q90);
  sv[t] = dc;
  __syncthreads();
  for (int s = 128; s > 0; s >>= 1) {
    if (t < s) sv[t] += sv[t + s];
    __syncthreads();
  }
  const float mean = sv[0] * (1.0f / 256.f);
  invd[t] = mean / (0.1f * dc);
}

// ---- k5: MFMA GEMM (128 rows x 256 groups, K=512) + fused softmax loss ----
#define ARS 144   // A row stride bytes (64 bf16 + 8 pad)
#define BRS 144
__global__ __launch_bounds__(256, 2) void k5_mfma(const ushort* __restrict__ Xb,
    const ushort* __restrict__ centB, const int* __restrict__ subject,
    const int* __restrict__ labels, const float* __restrict__ invd,
    float* __restrict__ losssum) {
  __shared__ char smem[128 * ARS + 256 * BRS + 1024];
  char* ldsA = smem;                 // [128][144B]
  char* ldsB = smem + 128 * ARS;     // [256][144B]
  float* maxbuf = (float*)smem;      // epilogue aliases ldsA: [4][128]
  float* gmax = (float*)(smem + 2048);    // [128]
  float* ebuf = (float*)(smem + 2560);    // [4][128]
  float* zbuf = (float*)(smem + 4608);    // [4][128]
  int* labs = (int*)(smem + 128 * ARS + 256 * BRS);
  int* subs = labs + 128;

  const int t = threadIdx.x;
  const int w = t >> 6;
  const int lane = t & 63;
  const int quad = lane >> 4;
  const int n16 = lane & 15;
  const int rowbase = blockIdx.x * 128;

  if (t < 128) {
    int b = (rowbase + t) & (BN - 1);
    labs[t] = labels[b];
    subs[t] = subject[b];
  }

  f32x4 acc[8][4];
#pragma unroll
  for (int mt = 0; mt < 8; ++mt)
#pragma unroll
    for (int nt = 0; nt < 4; ++nt) acc[mt][nt] = (f32x4){0.f, 0.f, 0.f, 0.f};

  const ushort* Arow = Xb + (size_t)rowbase * DN;

  for (int k0 = 0; k0 < DN; k0 += 64) {
    __syncthreads();
#pragma unroll
    for (int i = 0; i < 4; ++i) {
      int j = t + i * 256;
      int r = j >> 3, c = j & 7;
      *(int4*)(ldsA + r * ARS + c * 16) =
          *(const int4*)(Arow + (size_t)r * DN + k0 + c * 8);
    }
#pragma unroll
    for (int i = 0; i < 8; ++i) {
      int j = t + i * 256;
      int g = j >> 3, c = j & 7;
      *(int4*)(ldsB + g * BRS + c * 16) =
          *(const int4*)(centB + (size_t)g * DN + k0 + c * 8);
    }
    __syncthreads();
#pragma unroll
    for (int s = 0; s < 2; ++s) {
      bf16x8 bfr[4];
#pragma unroll
      for (int nt = 0; nt < 4; ++nt) {
        int g = w * 64 + nt * 16 + n16;
        bfr[nt] = *(bf16x8*)(ldsB + g * BRS + s * 64 + quad * 16);
      }
#pragma unroll
      for (int mt = 0; mt < 8; ++mt) {
        bf16x8 afr = *(bf16x8*)(ldsA + (mt * 16 + n16) * ARS + s * 64 + quad * 16);
#pragma unroll
        for (int nt = 0; nt < 4; ++nt)
          acc[mt][nt] = __builtin_amdgcn_mfma_f32_16x16x32_bf16(afr, bfr[nt], acc[mt][nt], 0, 0, 0);
      }
    }
  }

  float iv[4];
#pragma unroll
  for (int nt = 0; nt < 4; ++nt) iv[nt] = invd[w * 64 + nt * 16 + n16];

  __syncthreads();

#pragma unroll
  for (int mt = 0; mt < 8; ++mt) {
#pragma unroll
    for (int r = 0; r < 4; ++r) {
      float mm = -INFINITY;
#pragma unroll
      for (int nt = 0; nt < 4; ++nt) mm = fmaxf(mm, acc[mt][nt][r] * iv[nt]);
#pragma unroll
      for (int off = 1; off < 16; off <<= 1) mm = fmaxf(mm, __shfl_xor(mm, off, 64));
      if (n16 == 0) maxbuf[w * 128 + mt * 16 + quad * 4 + r] = mm;
    }
  }
  __syncthreads();
  if (t < 128)
    gmax[t] = fmaxf(fmaxf(maxbuf[t], maxbuf[128 + t]),
                    fmaxf(maxbuf[256 + t], maxbuf[384 + t]));
  __syncthreads();

#pragma unroll
  for (int mt = 0; mt < 8; ++mt) {
#pragma unroll
    for (int r = 0; r < 4; ++r) {
      const int row = mt * 16 + quad * 4 + r;
      const float gm = gmax[row];
      const int lab = labs[row];
      const int sub = subs[row];
      float e = 0.f, z = 0.f;
      if ((n16 & 7) == lab) {
#pragma unroll
        for (int nt = 0; nt < 4; ++nt) {
          int gdiv8 = w * 8 + nt * 2 + (n16 >> 3);
          if (gdiv8 != sub) {
            float sv = acc[mt][nt][r] * iv[nt] - gm;
            e += expf(sv);
            z += sv;
          }
        }
      }
#pragma unroll
      for (int off = 1; off < 16; off <<= 1) {
        e += __shfl_xor(e, off, 64);
        z += __shfl_xor(z, off, 64);
      }
      if (n16 == 0) {
        ebuf[w * 128 + row] = e;
        zbuf[w * 128 + row] = z;
      }
    }
  }
  __syncthreads();

  float lsum = 0.f;
  if (t < 128) {
    float e = ebuf[t] + ebuf[128 + t] + ebuf[256 + t] + ebuf[384 + t];
    float z = zbuf[t] + zbuf[128 + t] + zbuf[256 + t] + zbuf[384 + t];
    lsum = logf(225.f + e) - z * (1.0f / 31.0f);
  }
#pragma unroll
  for (int off = 32; off > 0; off >>= 1) lsum += __shfl_down(lsum, off, 64);
  if (lane == 0 && lsum != 0.f) atomAddF(losssum, lsum);
}

// ---- k6: final mean ----
__global__ void k6_final(const float* __restrict__ losssum, float* __restrict__ out) {
  out[0] = losssum[0] * (1.0f / (float)N2);
}

extern "C" void kernel_launch(void* const* d_in, const int* in_sizes, int n_in,
                              void* d_out, int out_size, void* d_ws, size_t ws_size,
                              hipStream_t stream) {
  const float* X = (const float*)d_in[0];
  const int* subject = (const int*)d_in[1];
  const int* labels = (const int*)d_in[2];
  char* ws = (char*)d_ws;
  ushort* Xb = (ushort*)(ws + OFF_XBF);
  float* partial = (float*)(ws + OFF_PART);
  float* sums = (float*)(ws + OFF_SUMS);
  ushort* centB = (ushort*)(ws + OFF_CENTB);
  int* gid = (int*)(ws + OFF_GID);
  int* perm = (int*)(ws + OFF_PERM);
  int* basep = (int*)(ws + OFF_BASE);
  int* offw = (int*)(ws + OFF_OFFW);
  int* counts = (int*)(ws + OFF_COUNTS);
  float* sumq = (float*)(ws + OFF_SUMQ);
  float* invd = (float*)(ws + OFF_INVD);
  float* losssum = (float*)(ws + OFF_LOSS);

  hipMemsetAsync(ws + ZERO_OFF, 0, ZERO_BYTES, stream);
  k0_gid<<<BN / 1024, 256, 0, stream>>>(subject, labels, gid, counts);
  k0b_scan<<<1, 256, 0, stream>>>(counts, basep, offw);
  k0c_scatter<<<BN / 256, 256, 0, stream>>>(gid, offw, perm);
  k1_sums<<<KN * SPLIT, 256, 0, stream>>>(X, perm, basep, Xb, partial);
  k1b_cent<<<(KN * DN) / 256, 256, 0, stream>>>(partial, counts, sums, centB);
  k3_dist<<<KN * SPLIT, 256, 0, stream>>>(Xb, perm, basep, sums, counts, sumq);
  k4_density<<<1, 256, 0, stream>>>(sumq, counts, invd);
  k5_mfma<<<N2 / 128, 256, 0, stream>>>(Xb, centB, subject, labels, invd, losssum);
  k6_final<<<1, 1, 0, stream>>>(losssum, (float*)d_out);
}

// Round 6
// 313.007 us; speedup vs baseline: 1.8018x; 1.0036x over previous
//
#include <hip/hip_runtime.h>
#include <math.h>

// Problem constants
#define BN 32768
#define DN 512
#define SN 32
#define LN 8
#define KN 256
#define N2 65536   // 2*BN
#define SPLIT 8    // blocks per group in k1/k3

typedef __attribute__((ext_vector_type(8))) short bf16x8;
typedef __attribute__((ext_vector_type(4))) float f32x4;

// workspace layout (byte offsets)
#define OFF_XBF     0ull            // ushort[N2*DN]            67108864
#define OFF_PART    67108864ull     // float[SPLIT*KN*DN]        4194304
#define OFF_SUMS    71303168ull     // float[KN*DN]               524288
#define OFF_CENTB   71827456ull     // ushort[KN*DN]              262144
#define OFF_GID     72089600ull     // int[BN]                    131072
#define OFF_PERM    72220672ull     // int[BN]                    131072
#define OFF_BASE    72351744ull     // int[KN+1]
#define OFF_OFFW    72352772ull     // int[KN]
#define OFF_COUNTS  72353796ull     // int[KN]
#define OFF_SUMQ    72354820ull     // float[KN]
#define OFF_INVD    72355844ull     // float[KN]
#define OFF_LOSS    72356868ull     // float[1]
#define ZERO_OFF    OFF_COUNTS
#define ZERO_BYTES  (72356872ull - OFF_COUNTS)

__device__ __forceinline__ float atomAddF(float* p, float v) {
  return unsafeAtomicAdd(p, v);   // hw global_atomic_add_f32
}

__device__ __forceinline__ ushort f2bf(float x) {
  union { float f; unsigned u; } v; v.f = x;
  unsigned u = v.u;
  unsigned r = (u + 0x7fffu + ((u >> 16) & 1u)) >> 16;  // RNE
  return (ushort)r;
}

__device__ __forceinline__ float bf2f(ushort x) {
  union { unsigned u; float f; } v; v.u = ((unsigned)x) << 16;
  return v.f;
}

// async 16B/lane global->LDS DMA (lands at lds base + lane*16)
__device__ __forceinline__ void async16(const void* g, void* l) {
  __builtin_amdgcn_global_load_lds(
      (const __attribute__((address_space(1))) unsigned int*)g,
      (__attribute__((address_space(3))) unsigned int*)l, 16, 0, 0);
}

// ---- k0a: gid + counts histogram ----
__global__ __launch_bounds__(256) void k0_gid(const int* __restrict__ subject,
    const int* __restrict__ labels, int* __restrict__ gid, int* __restrict__ counts) {
  __shared__ int hist[KN];
  hist[threadIdx.x] = 0;
  __syncthreads();
  const int b0 = blockIdx.x * 1024;
  for (int i = threadIdx.x; i < 1024; i += 256) {
    int b = b0 + i;
    int g = subject[b] * LN + labels[b];
    gid[b] = g;
    atomicAdd(&hist[g], 1);
  }
  __syncthreads();
  if (hist[threadIdx.x]) atomicAdd(&counts[threadIdx.x], 2 * hist[threadIdx.x]);
}

// ---- k0b: exclusive scan of per-group row counts -> base, offw ----
__global__ __launch_bounds__(256) void k0b_scan(const int* __restrict__ counts,
    int* __restrict__ base, int* __restrict__ offw) {
  __shared__ int sh[KN];
  const int t = threadIdx.x;
  const int h = counts[t] >> 1;   // rows (not x2 views)
  sh[t] = h;
  __syncthreads();
  for (int d = 1; d < 256; d <<= 1) {
    int add = (t >= d) ? sh[t - d] : 0;
    __syncthreads();
    sh[t] += add;
    __syncthreads();
  }
  const int excl = sh[t] - h;
  base[t] = excl;
  offw[t] = excl;
  if (t == 255) base[256] = sh[255];
}

// ---- k0c: counting-sort scatter -> perm ----
__global__ __launch_bounds__(256) void k0c_scatter(const int* __restrict__ gid,
    int* __restrict__ offw, int* __restrict__ perm) {
  const int b = blockIdx.x * 256 + threadIdx.x;
  const int g = gid[b];
  const int pos = atomicAdd(&offw[g], 1);
  perm[pos] = b;
}

// ---- k1: sorted segment-reduce group sums + f32->bf16 conversion ----
__global__ __launch_bounds__(256) void k1_sums(const float* __restrict__ X,
    const int* __restrict__ perm, const int* __restrict__ base,
    ushort* __restrict__ Xb, float* __restrict__ partial) {
  __shared__ float buf[512];
  const int g = blockIdx.x >> 3;
  const int s = blockIdx.x & (SPLIT - 1);
  const int t = threadIdx.x;
  const int start = base[g], end = base[g + 1];

  float4 acc = {0.f, 0.f, 0.f, 0.f};
  int i = start + s;
  if (i < end) {
    int idx = perm[i];
    float4 x = *(const float4*)(X + (size_t)idx * 1024 + t * 4);
    while (true) {
      const int inext = i + SPLIT;
      int idxn = idx;
      float4 xn = x;
      if (inext < end) {
        idxn = perm[inext];
        xn = *(const float4*)(X + (size_t)idxn * 1024 + t * 4);
      }
      acc.x += x.x; acc.y += x.y; acc.z += x.z; acc.w += x.w;
      ushort4 u = {f2bf(x.x), f2bf(x.y), f2bf(x.z), f2bf(x.w)};
      const size_t dst = (t < 128) ? ((size_t)idx * DN + t * 4)
                                   : ((size_t)(idx + BN) * DN + (t - 128) * 4);
      *(ushort4*)(Xb + dst) = u;
      if (inext >= end) break;
      i = inext; idx = idxn; x = xn;
    }
  }
  if (t >= 128) *(float4*)&buf[(t - 128) * 4] = acc;
  __syncthreads();
  if (t < 128) {
    float4 o = *(float4*)&buf[t * 4];
    float4 out = {acc.x + o.x, acc.y + o.y, acc.z + o.z, acc.w + o.w};
    *(float4*)&partial[((size_t)s * KN + g) * DN + t * 4] = out;
  }
}

// ---- k1b: reduce split partials -> sums + bf16 centroids ----
__global__ __launch_bounds__(256) void k1b_cent(const float* __restrict__ partial,
    const int* __restrict__ counts, float* __restrict__ sums,
    ushort* __restrict__ centB) {
  const int i = blockIdx.x * 256 + threadIdx.x;   // over KN*DN, [g][d]
  const int g = i >> 9;
  float ss = 0.f;
#pragma unroll
  for (int s = 0; s < SPLIT; ++s) ss += partial[(size_t)s * (KN * DN) + i];
  sums[i] = ss;
  centB[i] = f2bf(ss / (float)counts[g]);
}

// ---- k3: group-per-block distance^0.25 accumulation, 1 atomic/block ----
__global__ __launch_bounds__(256) void k3_dist(const ushort* __restrict__ Xb,
    const int* __restrict__ perm, const int* __restrict__ base,
    const float* __restrict__ sums, const int* __restrict__ counts,
    float* __restrict__ sumq) {
  __shared__ float wacc[4];
  const int g = blockIdx.x >> 3;
  const int s = blockIdx.x & (SPLIT - 1);
  const int t = threadIdx.x;
  const int w = t >> 6;
  const int lane = t & 63;
  const int start = base[g], end = base[g + 1];
  const int nviews = 2 * (end - start);
  const float invc = 1.0f / (float)counts[g];
  const float* sp = sums + g * DN + lane * 8;
  float4 c0 = *(const float4*)sp;
  float4 c1 = *(const float4*)(sp + 4);
  const float cs[8] = {c0.x * invc, c0.y * invc, c0.z * invc, c0.w * invc,
                       c1.x * invc, c1.y * invc, c1.z * invc, c1.w * invc};
  float q = 0.f;
  const int vs = s * 4 + w;   // virtual split 0..31
  for (int j = vs; j < nviews; j += SPLIT * 4) {
    const int idx = perm[start + (j >> 1)];
    const int row = idx + (j & 1) * BN;
    int4 chunk = *(const int4*)(Xb + (size_t)row * DN + lane * 8);
    const ushort* us = (const ushort*)&chunk;
    float ss = 0.f;
#pragma unroll
    for (int k = 0; k < 8; ++k) {
      float diff = bf2f(us[k]) - cs[k];
      ss += diff * diff;
    }
#pragma unroll
    for (int off = 32; off > 0; off >>= 1) ss += __shfl_down(ss, off, 64);
    if (lane == 0) q += sqrtf(sqrtf(ss));
  }
  if (lane == 0) wacc[w] = q;
  __syncthreads();
  if (t == 0) atomAddF(&sumq[g], wacc[0] + wacc[1] + wacc[2] + wacc[3]);
}

// ---- k4: density -> invd ----
__global__ __launch_bounds__(256) void k4_density(const float* __restrict__ sumq,
    const int* __restrict__ counts, float* __restrict__ invd) {
  __shared__ float sv[256];
  __shared__ float st[256];
  const int t = threadIdx.x;
  const int cnt = counts[t];
  const bool valid = cnt > 1;
  float dens = 0.f;
  if (valid) dens = (sumq[t] / (float)cnt) / logf((float)cnt + 10.f);
  sv[t] = valid ? dens : -INFINITY;
  __syncthreads();
  for (int s = 128; s > 0; s >>= 1) {
    if (t < s) sv[t] = fmaxf(sv[t], sv[t + s]);
    __syncthreads();
  }
  const float dmax = sv[0];
  __syncthreads();
  const float d0 = valid ? dens : dmax;
  sv[t] = d0;
  __syncthreads();
  int rank = 0;
  for (int j = 0; j < 256; ++j) {
    float vj = sv[j];
    rank += (vj < d0) || (vj == d0 && j < t);
  }
  st[rank] = d0;
  __syncthreads();
  const float q10 = 0.5f * (st[25] + st[26]);
  const float q90 = 0.5f * (st[229] + st[230]);
  const float dc = fminf(fmaxf(d0, q10), q90);
  sv[t] = dc;
  __syncthreads();
  for (int s = 128; s > 0; s >>= 1) {
    if (t < s) sv[t] += sv[t + s];
    __syncthreads();
  }
  const float mean = sv[0] * (1.0f / 256.f);
  invd[t] = mean / (0.1f * dc);
}

// ---- k5: MFMA GEMM (128 rows x 256 groups, K=512) + fused softmax loss ----
// global_load_lds staging, unpadded 128B rows + XOR-swizzled chunk layout:
// chunk c of row r lives at lds r*128 + (c ^ (r&7))*16. Swizzle is inverted on
// the *source* address (lane slot i carries global chunk (i%8)^(i/8)), so the
// DMA's contiguous lane->slot mapping produces the swizzled image. Fragment
// reads then spread across all 32 banks at 2 lanes/bank (free, m136).
#define TAB (128 * 128)   // A tile bytes
#define TBB (256 * 128)   // B tile bytes
__global__ __launch_bounds__(256, 2) void k5_mfma(const ushort* __restrict__ Xb,
    const ushort* __restrict__ centB, const int* __restrict__ subject,
    const int* __restrict__ labels, const float* __restrict__ invd,
    float* __restrict__ losssum) {
  __shared__ char smem[TAB + TBB + 1024];
  char* ldsA = smem;                 // [128 rows][128B, swizzled]
  char* ldsB = smem + TAB;           // [256 rows][128B, swizzled]
  float* maxbuf = (float*)smem;      // epilogue aliases ldsA: [4][128]
  float* gmax = (float*)(smem + 2048);    // [128]
  float* ebuf = (float*)(smem + 2560);    // [4][128]
  float* zbuf = (float*)(smem + 4608);    // [4][128]
  int* labs = (int*)(smem + TAB + TBB);
  int* subs = labs + 128;

  const int t = threadIdx.x;
  const int w = t >> 6;
  const int lane = t & 63;
  const int quad = lane >> 4;
  const int n16 = lane & 15;
  const int li = lane >> 3;          // row within an 8-row DMA chunk
  const int lc = lane & 7;           // lds slot chunk
  const int srcc = lc ^ li;          // swizzled source chunk
  const int rowbase = blockIdx.x * 128;

  if (t < 128) {
    int b = (rowbase + t) & (BN - 1);
    labs[t] = labels[b];
    subs[t] = subject[b];
  }

  f32x4 acc[8][4];
#pragma unroll
  for (int mt = 0; mt < 8; ++mt)
#pragma unroll
    for (int nt = 0; nt < 4; ++nt) acc[mt][nt] = (f32x4){0.f, 0.f, 0.f, 0.f};

  const ushort* Arow = Xb + (size_t)rowbase * DN;

  for (int k0 = 0; k0 < DN; k0 += 64) {
    __syncthreads();
    // A: wave w stages rows [w*32, w*32+32) in 4 DMA calls of 8 rows
#pragma unroll
    for (int q = 0; q < 4; ++q) {
      const int r0 = w * 32 + q * 8;
      async16(Arow + (size_t)(r0 + li) * DN + k0 + srcc * 8, ldsA + r0 * 128);
    }
    // B: wave w stages groups [w*64, w*64+64) in 8 DMA calls
#pragma unroll
    for (int q = 0; q < 8; ++q) {
      const int g0 = w * 64 + q * 8;
      async16(centB + (size_t)(g0 + li) * DN + k0 + srcc * 8, ldsB + g0 * 128);
    }
    __syncthreads();
#pragma unroll
    for (int s = 0; s < 2; ++s) {
      const int csw = ((s * 4 + quad) ^ (n16 & 7)) * 16;
      bf16x8 bfr[4];
#pragma unroll
      for (int nt = 0; nt < 4; ++nt) {
        int g = w * 64 + nt * 16 + n16;
        bfr[nt] = *(bf16x8*)(ldsB + g * 128 + csw);
      }
#pragma unroll
      for (int mt = 0; mt < 8; ++mt) {
        bf16x8 afr = *(bf16x8*)(ldsA + (mt * 16 + n16) * 128 + csw);
#pragma unroll
        for (int nt = 0; nt < 4; ++nt)
          acc[mt][nt] = __builtin_amdgcn_mfma_f32_16x16x32_bf16(afr, bfr[nt], acc[mt][nt], 0, 0, 0);
      }
    }
  }

  float iv[4];
#pragma unroll
  for (int nt = 0; nt < 4; ++nt) iv[nt] = invd[w * 64 + nt * 16 + n16];

  __syncthreads();

#pragma unroll
  for (int mt = 0; mt < 8; ++mt) {
#pragma unroll
    for (int r = 0; r < 4; ++r) {
      float mm = -INFINITY;
#pragma unroll
      for (int nt = 0; nt < 4; ++nt) mm = fmaxf(mm, acc[mt][nt][r] * iv[nt]);
#pragma unroll
      for (int off = 1; off < 16; off <<= 1) mm = fmaxf(mm, __shfl_xor(mm, off, 64));
      if (n16 == 0) maxbuf[w * 128 + mt * 16 + quad * 4 + r] = mm;
    }
  }
  __syncthreads();
  if (t < 128)
    gmax[t] = fmaxf(fmaxf(maxbuf[t], maxbuf[128 + t]),
                    fmaxf(maxbuf[256 + t], maxbuf[384 + t]));
  __syncthreads();

#pragma unroll
  for (int mt = 0; mt < 8; ++mt) {
#pragma unroll
    for (int r = 0; r < 4; ++r) {
      const int row = mt * 16 + quad * 4 + r;
      const float gm = gmax[row];
      const int lab = labs[row];
      const int sub = subs[row];
      float e = 0.f, z = 0.f;
      if ((n16 & 7) == lab) {
#pragma unroll
        for (int nt = 0; nt < 4; ++nt) {
          int gdiv8 = w * 8 + nt * 2 + (n16 >> 3);
          if (gdiv8 != sub) {
            float sv = acc[mt][nt][r] * iv[nt] - gm;
            e += expf(sv);
            z += sv;
          }
        }
      }
#pragma unroll
      for (int off = 1; off < 16; off <<= 1) {
        e += __shfl_xor(e, off, 64);
        z += __shfl_xor(z, off, 64);
      }
      if (n16 == 0) {
        ebuf[w * 128 + row] = e;
        zbuf[w * 128 + row] = z;
      }
    }
  }
  __syncthreads();

  float lsum = 0.f;
  if (t < 128) {
    float e = ebuf[t] + ebuf[128 + t] + ebuf[256 + t] + ebuf[384 + t];
    float z = zbuf[t] + zbuf[128 + t] + zbuf[256 + t] + zbuf[384 + t];
    lsum = logf(225.f + e) - z * (1.0f / 31.0f);
  }
#pragma unroll
  for (int off = 32; off > 0; off >>= 1) lsum += __shfl_down(lsum, off, 64);
  if (lane == 0 && lsum != 0.f) atomAddF(losssum, lsum);
}

// ---- k6: final mean ----
__global__ void k6_final(const float* __restrict__ losssum, float* __restrict__ out) {
  out[0] = losssum[0] * (1.0f / (float)N2);
}

extern "C" void kernel_launch(void* const* d_in, const int* in_sizes, int n_in,
                              void* d_out, int out_size, void* d_ws, size_t ws_size,
                              hipStream_t stream) {
  const float* X = (const float*)d_in[0];
  const int* subject = (const int*)d_in[1];
  const int* labels = (const int*)d_in[2];
  char* ws = (char*)d_ws;
  ushort* Xb = (ushort*)(ws + OFF_XBF);
  float* partial = (float*)(ws + OFF_PART);
  float* sums = (float*)(ws + OFF_SUMS);
  ushort* centB = (ushort*)(ws + OFF_CENTB);
  int* gid = (int*)(ws + OFF_GID);
  int* perm = (int*)(ws + OFF_PERM);
  int* basep = (int*)(ws + OFF_BASE);
  int* offw = (int*)(ws + OFF_OFFW);
  int* counts = (int*)(ws + OFF_COUNTS);
  float* sumq = (float*)(ws + OFF_SUMQ);
  float* invd = (float*)(ws + OFF_INVD);
  float* losssum = (float*)(ws + OFF_LOSS);

  hipMemsetAsync(ws + ZERO_OFF, 0, ZERO_BYTES, stream);
  k0_gid<<<BN / 1024, 256, 0, stream>>>(subject, labels, gid, counts);
  k0b_scan<<<1, 256, 0, stream>>>(counts, basep, offw);
  k0c_scatter<<<BN / 256, 256, 0, stream>>>(gid, offw, perm);
  k1_sums<<<KN * SPLIT, 256, 0, stream>>>(X, perm, basep, Xb, partial);
  k1b_cent<<<(KN * DN) / 256, 256, 0, stream>>>(partial, counts, sums, centB);
  k3_dist<<<KN * SPLIT, 256, 0, stream>>>(Xb, perm, basep, sums, counts, sumq);
  k4_density<<<1, 256, 0, stream>>>(sumq, counts, invd);
  k5_mfma<<<N2 / 128, 256, 0, stream>>>(Xb, centB, subject, labels, invd, losssum);
  k6_final<<<1, 1, 0, stream>>>(losssum, (float*)d_out);
}